// Round 1
// baseline (78.963 us; speedup 1.0000x reference)
//
#include <hip/hip_runtime.h>
#include <stdint.h>

#define H 1024
#define BATCH 2048
#define KDIM 2048   // input + hidden concatenated
#define NDIM 4096   // 4 gates
#define EPS 1e-5f

#define BM 128
#define BN 128
#define BK 64

typedef __attribute__((ext_vector_type(8))) short bf16x8;
typedef __attribute__((ext_vector_type(4))) float f32x4;

__device__ __forceinline__ unsigned short f2bf(float f) {
  uint32_t u = __float_as_uint(f);
  u += 0x7FFFu + ((u >> 16) & 1u);
  return (unsigned short)(u >> 16);
}

__device__ __forceinline__ float fast_sig(float x) {
  x = fminf(30.f, fmaxf(-30.f, x));
  float e = __expf(x);
  return e / (e + 1.f);
}

__device__ __forceinline__ float fast_tanh(float x) {
  x = fminf(15.f, fmaxf(-15.f, x));
  float e = __expf(2.f * x);
  return (e - 1.f) / (e + 1.f);
}

// ---------------- pack: f32 -> bf16, concat along K ----------------
// A[2048][2048] <- [x | h],  B[4096][2048] <- [W_ih | W_hh]
__global__ __launch_bounds__(256) void pack_kernel(
    const float* __restrict__ x, const float* __restrict__ h,
    const float* __restrict__ Wih, const float* __restrict__ Whh,
    unsigned short* __restrict__ A, unsigned short* __restrict__ B) {
  int u = blockIdx.x * 256 + threadIdx.x;  // one float4 unit per thread
  const int unitsA = BATCH * KDIM / 4;     // 1048576
  const float* src;
  unsigned short* dst;
  if (u < unitsA) {
    int m = u >> 9;              // KDIM/4 = 512 units per row
    int kv = (u & 511) << 2;
    src = (kv < H) ? (x + (size_t)m * H + kv) : (h + (size_t)m * H + (kv - H));
    dst = A + (size_t)m * KDIM + kv;
  } else {
    int v = u - unitsA;
    int m = v >> 9;
    int kv = (v & 511) << 2;
    src = (kv < H) ? (Wih + (size_t)m * H + kv) : (Whh + (size_t)m * H + (kv - H));
    dst = B + (size_t)m * KDIM + kv;
  }
  float4 f = *(const float4*)src;
  ushort4 o;
  o.x = f2bf(f.x);
  o.y = f2bf(f.y);
  o.z = f2bf(f.z);
  o.w = f2bf(f.w);
  *(ushort4*)dst = o;
}

// ---------------- GEMM: preact = A @ B^T (bf16 -> f32) ----------------
__device__ __forceinline__ void load_lds16(const void* g, void* l) {
  __builtin_amdgcn_global_load_lds(
      (const __attribute__((address_space(1))) void*)g,
      (__attribute__((address_space(3))) void*)l, 16, 0, 0);
}

__global__ __launch_bounds__(256) void gemm_kernel(
    const unsigned short* __restrict__ A,  // 2048 x 2048 bf16
    const unsigned short* __restrict__ B,  // 4096 x 2048 bf16 (B^T layout)
    float* __restrict__ C) {               // 2048 x 4096 f32
  __shared__ unsigned short As[BM * BK];   // 16 KB
  __shared__ unsigned short Bs[BN * BK];   // 16 KB

  const int tid = threadIdx.x;
  const int wave = tid >> 6;
  const int lane = tid & 63;
  const int m0 = blockIdx.y * BM;
  const int n0 = blockIdx.x * BN;
  const int wr = (wave >> 1) * 64;  // wave quadrant rows
  const int wc = (wave & 1) * 64;   // wave quadrant cols

  f32x4 acc[4][4] = {};

  const int srow = tid >> 3;        // staging row within 32-row slab
  const int scol = (tid & 7) << 3;  // staging col (elements)
  const int frow = lane & 15;       // fragment row
  const int fk = (lane >> 4) << 3;  // fragment k offset

  for (int k0 = 0; k0 < KDIM; k0 += BK) {
#pragma unroll
    for (int q = 0; q < 4; ++q) {
      const int row = q * 32 + srow;
      const uint32_t loff = (uint32_t)(q * 4096 + wave * 1024);  // wave-uniform
      load_lds16(A + (size_t)(m0 + row) * KDIM + k0 + scol, (char*)As + loff);
      load_lds16(B + (size_t)(n0 + row) * KDIM + k0 + scol, (char*)Bs + loff);
    }
    asm volatile("s_waitcnt vmcnt(0)" ::: "memory");
    __syncthreads();

#pragma unroll
    for (int kk = 0; kk < BK; kk += 32) {
      bf16x8 a[4], b[4];
#pragma unroll
      for (int i = 0; i < 4; ++i) {
        a[i] = *(const bf16x8*)&As[(wr + i * 16 + frow) * BK + kk + fk];
        b[i] = *(const bf16x8*)&Bs[(wc + i * 16 + frow) * BK + kk + fk];
      }
#pragma unroll
      for (int i = 0; i < 4; ++i)
#pragma unroll
        for (int j = 0; j < 4; ++j)
          acc[i][j] =
              __builtin_amdgcn_mfma_f32_16x16x32_bf16(a[i], b[j], acc[i][j], 0, 0, 0);
    }
    __syncthreads();
  }

  const int crow = (lane >> 4) << 2;
  const int ccol = lane & 15;
#pragma unroll
  for (int i = 0; i < 4; ++i)
#pragma unroll
    for (int j = 0; j < 4; ++j) {
      float* cp = C + (size_t)(m0 + wr + i * 16 + crow) * NDIM + (n0 + wc + j * 16 + ccol);
#pragma unroll
      for (int r = 0; r < 4; ++r) cp[(size_t)r * NDIM] = acc[i][j][r];
    }
}

// ---------------- epilogue: gates + c update + LayerNorm + h ----------------
__global__ __launch_bounds__(256) void epilogue_kernel(
    const float* __restrict__ P,     // 2048 x 4096 preact (no bias)
    const float* __restrict__ c_in,  // 2048 x 1024
    const float* __restrict__ b_ih, const float* __restrict__ b_hh,
    const float* __restrict__ ln_w, const float* __restrict__ ln_b,
    float* __restrict__ h_out, float* __restrict__ c_out) {
  const int m = blockIdx.x;
  const int t = threadIdx.x;
  const int j = t << 2;  // 4 elements per thread, 256 threads -> 1024
  const float* row = P + (size_t)m * NDIM;

  float4 pi = *(const float4*)(row + 0 * H + j);
  float4 pf = *(const float4*)(row + 1 * H + j);
  float4 po = *(const float4*)(row + 2 * H + j);
  float4 pg = *(const float4*)(row + 3 * H + j);
  float4 ci = *(const float4*)(c_in + (size_t)m * H + j);

  float4 bi = *(const float4*)(b_ih + 0 * H + j);
  float4 bf = *(const float4*)(b_ih + 1 * H + j);
  float4 bo = *(const float4*)(b_ih + 2 * H + j);
  float4 bg = *(const float4*)(b_ih + 3 * H + j);
  float4 hi = *(const float4*)(b_hh + 0 * H + j);
  float4 hf = *(const float4*)(b_hh + 1 * H + j);
  float4 ho_ = *(const float4*)(b_hh + 2 * H + j);
  float4 hg = *(const float4*)(b_hh + 3 * H + j);

  float cr[4], vo[4];
  float s = 0.f, q = 0.f;
#pragma unroll
  for (int r = 0; r < 4; ++r) {
    float iv = fast_sig(((const float*)&pi)[r] + ((const float*)&bi)[r] + ((const float*)&hi)[r]);
    float fv = fast_sig(((const float*)&pf)[r] + ((const float*)&bf)[r] + ((const float*)&hf)[r]);
    float ov = fast_sig(((const float*)&po)[r] + ((const float*)&bo)[r] + ((const float*)&ho_)[r]);
    float gv = fast_tanh(((const float*)&pg)[r] + ((const float*)&bg)[r] + ((const float*)&hg)[r]);
    float cv = ((const float*)&ci)[r] * fv + iv * gv;
    cr[r] = cv;
    vo[r] = ov;
    s += cv;
    q += cv * cv;
  }

#pragma unroll
  for (int off = 32; off > 0; off >>= 1) {
    s += __shfl_xor(s, off);
    q += __shfl_xor(q, off);
  }
  __shared__ float red[8];
  const int wv = t >> 6, ln = t & 63;
  if (ln == 0) {
    red[wv] = s;
    red[wv + 4] = q;
  }
  __syncthreads();
  s = red[0] + red[1] + red[2] + red[3];
  q = red[4] + red[5] + red[6] + red[7];
  const float mu = s * (1.f / H);
  const float var = q * (1.f / H) - mu * mu;
  const float rstd = rsqrtf(var + EPS);

  float4 lw = *(const float4*)(ln_w + j);
  float4 lb = *(const float4*)(ln_b + j);
  float4 hov, cov;
#pragma unroll
  for (int r = 0; r < 4; ++r) {
    float cn = (cr[r] - mu) * rstd * ((const float*)&lw)[r] + ((const float*)&lb)[r];
    ((float*)&cov)[r] = cn;
    ((float*)&hov)[r] = vo[r] * fast_tanh(cn);
  }
  *(float4*)(h_out + (size_t)m * H + j) = hov;
  *(float4*)(c_out + (size_t)m * H + j) = cov;
}

extern "C" void kernel_launch(void* const* d_in, const int* in_sizes, int n_in,
                              void* d_out, int out_size, void* d_ws, size_t ws_size,
                              hipStream_t stream) {
  const float* x = (const float*)d_in[0];
  const float* h = (const float*)d_in[1];
  const float* c = (const float*)d_in[2];
  const float* Wih = (const float*)d_in[3];
  const float* b_ih = (const float*)d_in[4];
  const float* Whh = (const float*)d_in[5];
  const float* b_hh = (const float*)d_in[6];
  const float* ln_w = (const float*)d_in[7];
  const float* ln_b = (const float*)d_in[8];

  unsigned short* A = (unsigned short*)d_ws;  // 8 MB
  unsigned short* B = (unsigned short*)((char*)d_ws + (size_t)BATCH * KDIM * 2);  // 16 MB
  float* P = (float*)((char*)d_ws + (size_t)BATCH * KDIM * 2 + (size_t)NDIM * KDIM * 2);  // 32 MB

  float* h_out = (float*)d_out;
  float* c_out = (float*)d_out + (size_t)BATCH * H;

  pack_kernel<<<12288, 256, 0, stream>>>(x, h, Wih, Whh, A, B);
  dim3 g(NDIM / BN, BATCH / BM);
  gemm_kernel<<<g, 256, 0, stream>>>(A, B, P);
  epilogue_kernel<<<BATCH, 256, 0, stream>>>(P, c, b_ih, b_hh, ln_w, ln_b, h_out, c_out);
}

// Round 2
// 64.347 us; speedup vs baseline: 1.2271x; 1.2271x over previous
//
#include <hip/hip_runtime.h>
#include <hip/hip_fp16.h>
#include <stdint.h>

#define H 1024
#define BATCH 2048
#define KDIM 2048   // input + hidden concatenated
#define NDIM 4096   // 4 gates
#define EPS 1e-5f

#define BM 128
#define BN 128
#define BK 64

typedef __attribute__((ext_vector_type(8))) short bf16x8;
typedef __attribute__((ext_vector_type(4))) float f32x4;

__device__ __forceinline__ unsigned short f2bf(float f) {
  uint32_t u = __float_as_uint(f);
  u += 0x7FFFu + ((u >> 16) & 1u);
  return (unsigned short)(u >> 16);
}

__device__ __forceinline__ float fast_sig(float x) {
  x = fminf(30.f, fmaxf(-30.f, x));
  float e = __expf(x);
  return e / (e + 1.f);
}

__device__ __forceinline__ float fast_tanh(float x) {
  x = fminf(15.f, fmaxf(-15.f, x));
  float e = __expf(2.f * x);
  return (e - 1.f) / (e + 1.f);
}

// ---------------- pack: f32 -> bf16, concat along K ----------------
__global__ __launch_bounds__(256) void pack_kernel(
    const float* __restrict__ x, const float* __restrict__ h,
    const float* __restrict__ Wih, const float* __restrict__ Whh,
    unsigned short* __restrict__ A, unsigned short* __restrict__ B) {
  int u = blockIdx.x * 256 + threadIdx.x;
  const int unitsA = BATCH * KDIM / 4;
  const float* src;
  unsigned short* dst;
  if (u < unitsA) {
    int m = u >> 9;
    int kv = (u & 511) << 2;
    src = (kv < H) ? (x + (size_t)m * H + kv) : (h + (size_t)m * H + (kv - H));
    dst = A + (size_t)m * KDIM + kv;
  } else {
    int v = u - unitsA;
    int m = v >> 9;
    int kv = (v & 511) << 2;
    src = (kv < H) ? (Wih + (size_t)m * H + kv) : (Whh + (size_t)m * H + (kv - H));
    dst = B + (size_t)m * KDIM + kv;
  }
  float4 f = *(const float4*)src;
  ushort4 o;
  o.x = f2bf(f.x);
  o.y = f2bf(f.y);
  o.z = f2bf(f.z);
  o.w = f2bf(f.w);
  *(ushort4*)dst = o;
}

// ---------------- GEMM: P[z] = A @ B^T over K-half z (bf16 -> fp16 partials) --
__device__ __forceinline__ void load_lds16(const void* g, void* l) {
  __builtin_amdgcn_global_load_lds(
      (const __attribute__((address_space(1))) void*)g,
      (__attribute__((address_space(3))) void*)l, 16, 0, 0);
}

__global__ __launch_bounds__(256, 4) void gemm_kernel(
    const unsigned short* __restrict__ A,  // 2048 x 2048 bf16
    const unsigned short* __restrict__ B,  // 4096 x 2048 bf16 (B^T layout)
    __half* __restrict__ P0, __half* __restrict__ P1) {
  __shared__ unsigned short As[BM * BK];   // 16 KB
  __shared__ unsigned short Bs[BN * BK];   // 16 KB

  const int tid = threadIdx.x;
  const int wave = tid >> 6;
  const int lane = tid & 63;
  const int m0 = blockIdx.y * BM;
  const int n0 = blockIdx.x * BN;
  const int kbase = blockIdx.z * (KDIM / 2);
  __half* __restrict__ P = blockIdx.z ? P1 : P0;
  const int wr = (wave >> 1) * 64;
  const int wc = (wave & 1) * 64;

  f32x4 acc[4][4] = {};

  // staging: srow = tid>>3 (0..31), chunk = tid&7; pre-swizzle the GLOBAL
  // column chunk by srow&7 so the linear LDS write lands swizzled (rule 21)
  const int srow = tid >> 3;
  const int scol = (((tid & 7) ^ (srow & 7)) << 3);
  const int frow = lane & 15;
  const int fk = (lane >> 4) << 3;  // k element offset (0 or 8)

  for (int k0 = kbase; k0 < kbase + KDIM / 2; k0 += BK) {
#pragma unroll
    for (int q = 0; q < 4; ++q) {
      const int row = q * 32 + srow;
      const uint32_t loff = (uint32_t)(q * 4096 + wave * 1024);  // wave-uniform
      load_lds16(A + (size_t)(m0 + row) * KDIM + k0 + scol, (char*)As + loff);
      load_lds16(B + (size_t)(n0 + row) * KDIM + k0 + scol, (char*)Bs + loff);
    }
    asm volatile("s_waitcnt vmcnt(0)" ::: "memory");
    __syncthreads();

#pragma unroll
    for (int kk = 0; kk < BK; kk += 32) {
      bf16x8 a[4], b[4];
      const int kc = (kk + fk) >> 3;  // 16B chunk index within row
#pragma unroll
      for (int i = 0; i < 4; ++i) {
        const int ra = wr + i * 16 + frow;
        const int rb = wc + i * 16 + frow;
        a[i] = *(const bf16x8*)((const char*)As + ra * 128 + ((kc ^ (ra & 7)) << 4));
        b[i] = *(const bf16x8*)((const char*)Bs + rb * 128 + ((kc ^ (rb & 7)) << 4));
      }
#pragma unroll
      for (int i = 0; i < 4; ++i)
#pragma unroll
        for (int j = 0; j < 4; ++j)
          acc[i][j] =
              __builtin_amdgcn_mfma_f32_16x16x32_bf16(a[i], b[j], acc[i][j], 0, 0, 0);
    }
    __syncthreads();
  }

  const int crow = (lane >> 4) << 2;
  const int ccol = lane & 15;
#pragma unroll
  for (int i = 0; i < 4; ++i)
#pragma unroll
    for (int j = 0; j < 4; ++j) {
      __half* cp = P + (size_t)(m0 + wr + i * 16 + crow) * NDIM + (n0 + wc + j * 16 + ccol);
#pragma unroll
      for (int r = 0; r < 4; ++r) cp[(size_t)r * NDIM] = __float2half(acc[i][j][r]);
    }
}

// ---------------- epilogue: sum partials + gates + c update + LN + h --------
__global__ __launch_bounds__(256) void epilogue_kernel(
    const __half* __restrict__ P0, const __half* __restrict__ P1,
    const float* __restrict__ c_in,
    const float* __restrict__ b_ih, const float* __restrict__ b_hh,
    const float* __restrict__ ln_w, const float* __restrict__ ln_b,
    float* __restrict__ h_out, float* __restrict__ c_out) {
  const int m = blockIdx.x;
  const int t = threadIdx.x;
  const int j = t << 2;
  const __half* r0 = P0 + (size_t)m * NDIM;
  const __half* r1 = P1 + (size_t)m * NDIM;

  float pre[4][4];
#pragma unroll
  for (int g = 0; g < 4; ++g) {
    ushort4 u0 = *(const ushort4*)(r0 + g * H + j);
    ushort4 u1 = *(const ushort4*)(r1 + g * H + j);
    float4 bi = *(const float4*)(b_ih + g * H + j);
    float4 bh = *(const float4*)(b_hh + g * H + j);
    pre[g][0] = __half2float(*(__half*)&u0.x) + __half2float(*(__half*)&u1.x) + bi.x + bh.x;
    pre[g][1] = __half2float(*(__half*)&u0.y) + __half2float(*(__half*)&u1.y) + bi.y + bh.y;
    pre[g][2] = __half2float(*(__half*)&u0.z) + __half2float(*(__half*)&u1.z) + bi.z + bh.z;
    pre[g][3] = __half2float(*(__half*)&u0.w) + __half2float(*(__half*)&u1.w) + bi.w + bh.w;
  }
  float4 ci = *(const float4*)(c_in + (size_t)m * H + j);

  float cr[4], vo[4];
  float s = 0.f, q = 0.f;
#pragma unroll
  for (int r = 0; r < 4; ++r) {
    float iv = fast_sig(pre[0][r]);
    float fv = fast_sig(pre[1][r]);
    float ov = fast_sig(pre[2][r]);
    float gv = fast_tanh(pre[3][r]);
    float cv = ((const float*)&ci)[r] * fv + iv * gv;
    cr[r] = cv;
    vo[r] = ov;
    s += cv;
    q += cv * cv;
  }

#pragma unroll
  for (int off = 32; off > 0; off >>= 1) {
    s += __shfl_xor(s, off);
    q += __shfl_xor(q, off);
  }
  __shared__ float red[8];
  const int wv = t >> 6, ln = t & 63;
  if (ln == 0) {
    red[wv] = s;
    red[wv + 4] = q;
  }
  __syncthreads();
  s = red[0] + red[1] + red[2] + red[3];
  q = red[4] + red[5] + red[6] + red[7];
  const float mu = s * (1.f / H);
  const float var = q * (1.f / H) - mu * mu;
  const float rstd = rsqrtf(var + EPS);

  float4 lw = *(const float4*)(ln_w + j);
  float4 lb = *(const float4*)(ln_b + j);
  float4 hov, cov;
#pragma unroll
  for (int r = 0; r < 4; ++r) {
    float cn = (cr[r] - mu) * rstd * ((const float*)&lw)[r] + ((const float*)&lb)[r];
    ((float*)&cov)[r] = cn;
    ((float*)&hov)[r] = vo[r] * fast_tanh(cn);
  }
  *(float4*)(h_out + (size_t)m * H + j) = hov;
  *(float4*)(c_out + (size_t)m * H + j) = cov;
}

extern "C" void kernel_launch(void* const* d_in, const int* in_sizes, int n_in,
                              void* d_out, int out_size, void* d_ws, size_t ws_size,
                              hipStream_t stream) {
  const float* x = (const float*)d_in[0];
  const float* h = (const float*)d_in[1];
  const float* c = (const float*)d_in[2];
  const float* Wih = (const float*)d_in[3];
  const float* b_ih = (const float*)d_in[4];
  const float* Whh = (const float*)d_in[5];
  const float* b_hh = (const float*)d_in[6];
  const float* ln_w = (const float*)d_in[7];
  const float* ln_b = (const float*)d_in[8];

  unsigned short* A = (unsigned short*)d_ws;                                      // 8 MB
  unsigned short* B = (unsigned short*)((char*)d_ws + (size_t)BATCH * KDIM * 2);  // 16 MB
  char* pbase = (char*)d_ws + (size_t)BATCH * KDIM * 2 + (size_t)NDIM * KDIM * 2;
  __half* P0 = (__half*)pbase;                                    // 16 MB
  __half* P1 = (__half*)(pbase + (size_t)BATCH * NDIM * 2);       // 16 MB

  float* h_out = (float*)d_out;
  float* c_out = (float*)d_out + (size_t)BATCH * H;

  pack_kernel<<<12288, 256, 0, stream>>>(x, h, Wih, Whh, A, B);
  dim3 g(NDIM / BN, BATCH / BM, 2);
  gemm_kernel<<<g, 256, 0, stream>>>(A, B, P0, P1);
  epilogue_kernel<<<BATCH, 256, 0, stream>>>(P0, P1, c, b_ih, b_hh, ln_w, ln_b, h_out, c_out);
}